// Round 9
// baseline (76.771 us; speedup 1.0000x reference)
//
#include <hip/hip_runtime.h>

#define LOG2E 1.4426950408889634f
#define LN2F  0.6931471805599453f
#define RS5F  0.4472135954999579f  // 1/sqrt(5)

// single-instruction ds_swizzle (BitMode: src = ((lane & AND) | OR) ^ XOR, 32-lane groups)
template<int XOR, int OR, int AND>
__device__ __forceinline__ float swz(float v) {
    return __int_as_float(__builtin_amdgcn_ds_swizzle(
        __float_as_int(v), (XOR << 10) | (OR << 5) | AND));
}
#define SWZX(v, m) swz<(m), 0, 0x1F>(v)      // xor-butterfly (bits 0-3 stay in 16-group)
#define EXP2(x)  __builtin_amdgcn_exp2f(x)   // raw v_exp_f32
#define LOG2_(x) __builtin_amdgcn_logf(x)    // raw v_log_f32
#define RCP_(x)  __builtin_amdgcn_rcpf(x)    // raw v_rcp_f32

__device__ __forceinline__ float bperm(int byte_addr, float v) {
    return __int_as_float(__builtin_amdgcn_ds_bpermute(byte_addr, __float_as_int(v)));
}

// 8 items per WAVE as TWO independent sets of 4 (16-lane item groups, 32 items
// per 256-block). Within a set this is exactly the R8 structure; the two sets
// are independent register streams interleaved in program order so their
// DS-chain latencies (swizzle reductions, softmax refresh, bpermute fetches)
// overlap — in-wave ILP replacing the convoy TLP the single-set version lacks.
// Lane u = lane&15 holds state entry u (row=u>>2, col=u&3) of both its items.
// Combo digits: c1 = u>>2, c2 = u&3; in-lane j in [0,8): c0A = j>>2, c3A = j&3;
// C-combo = all-digit complement. Exactness: per-row max shifted out at load;
// no mid-round renorms (non-updated rows have max 0; softmax shift-invariant);
// single final renorm.
__global__ __launch_bounds__(256, 4) void mfnet_layer_kernel(
    const float* __restrict__ log_qi,   // (N,4,4)
    const float* __restrict__ G,        // (N,8,4)
    const float* __restrict__ sqrt_2rho,// (N,)
    const float* __restrict__ alpha_ptr,// (1,)
    float* __restrict__ out,            // (N,4,4)
    int N)
{
    const int tid  = threadIdx.x;
    const int wv   = tid >> 6;
    const int lane = tid & 63;
    const int grp  = (lane >> 4) & 3;    // item group within wave
    const int u    = lane & 15;
    const int ib   = blockIdx.x * 32 + wv * 8;   // wave's first item (8/wave)

    // G staging: 8 items x 32 floats, item stride 40 (bases at banks 0/8/16/24
    // per set -> conflict-free 16B group-broadcast reads). Wave-local, no barrier.
    __shared__ __align__(16) float sG[4][320];
    {
        size_t gidx = (size_t)ib * 32 + (size_t)(lane * 4);
        size_t gmax = (size_t)N * 32 - 4;
        if (gidx > gmax) gidx = gmax;
        float4 gv = *(const float4*)(G + gidx);
        *(float4*)&sG[wv][(lane >> 3) * 40 + (lane & 7) * 4] = gv;
    }

    const float alpha = alpha_ptr[0];
    const float alm1  = 1.0f - alpha;

    const int col = u & 3;               // state col, also c2
    const int row = u >> 2;              // state row, also c1

    // bpermute byte addresses (shared by both sets; group-relative)
    const int gb   = (lane & 0x30) << 2;
    const int aQ1A = gb + ((4 + row) << 2);          // q_row1[c1]
    const int aQ1C = gb + ((4 + (row ^ 3)) << 2);    // q_row1[c1^3]
    const int aR1  = gb + (col << 4);                // a lane whose c1 == col

    int   item[2]; bool valid[2];
    float rv[2], s1[2], s2[2], slqD[2];
#pragma unroll
    for (int s = 0; s < 2; ++s) {
        int it = ib + s * 4 + grp;
        valid[s] = (it < N);
        item[s]  = valid[s] ? it : (N - 1);
        rv[s] = sqrt_2rho[item[s]] * (RS5F * LOG2E);
        s1[s] = rv[s] * (float)(2 * row - 3);
        s2[s] = rv[s] * (float)(2 * col - 3);
        slqD[s] = log_qi[(size_t)item[s] * 16 + u] * LOG2E;
        float m1 = fmaxf(slqD[s], SWZX(slqD[s], 1));
        float m  = fmaxf(m1, SWZX(m1, 2));
        slqD[s] -= m;
    }

    // softmax of all rows at once (4-lane packs)
    auto softmax_all = [&](float sv) {
        float e   = EXP2(sv);
        float t   = e + SWZX(e, 1);
        float den = t + SWZX(t, 2);
        return e * RCP_(den);
    };

    float q1A[2], q1C[2], q2A[2], q2C[2];
    float q3v0[2], q3v1[2], q3v2[2], q3v3[2];
#pragma unroll
    for (int s = 0; s < 2; ++s) {
        float qD = softmax_all(slqD[s]);
        q1A[s]  = bperm(aQ1A, qD);  q1C[s] = bperm(aQ1C, qD);
        q2A[s]  = swz<0, 8, 0x13>(qD);     // q_row2[c2]
        q2C[s]  = swz<3, 8, 0x13>(qD);     // q_row2[c2^3]
        q3v0[s] = swz<0, 12, 0x10>(qD);    // q_row3[0..3] broadcast
        q3v1[s] = swz<0, 13, 0x10>(qD);
        q3v2[s] = swz<0, 14, 0x10>(qD);
        q3v3[s] = swz<0, 15, 0x10>(qD);
    }

    // ---- laplace-log-cdf accumulation (log2 units); pair trick C = -A ----
    float lpA[2][8] = {{0,0,0,0,0,0,0,0},{0,0,0,0,0,0,0,0}};
    float lpC[2][8] = {{0,0,0,0,0,0,0,0},{0,0,0,0,0,0,0,0}};
    const float* gw[2] = { &sG[wv][grp * 40], &sG[wv][(4 + grp) * 40] };
#pragma unroll
    for (int r = 0; r < 8; ++r) {
#pragma unroll
        for (int s = 0; s < 2; ++s) {
            float4 g  = *(const float4*)(gw[s] + r * 4);
            float b12 = fmaf(g.y, s1[s], g.z * s2[s]);
            float m0  = g.x * rv[s];
            float m3  = g.w * rv[s];
            float t0  = fmaf(m0, -3.0f, b12);   // c0 = 0
            float t1  = b12 - m0;               // c0 = 1
#pragma unroll
            for (int j = 0; j < 8; ++j) {
                float tb = (j & 4) ? t1 : t0;
                float t  = fmaf(m3, (float)(2 * (j & 3) - 3), tb);   // x*LOG2E
                float at = -fabsf(t);
                float e  = EXP2(at);
                float lg = LOG2_(fmaf(e, -0.5f, 1.0f));
                float ng = at - 1.0f;
                bool neg = (t < 0.0f);
                lpA[s][j] += neg ? ng : lg;
                lpC[s][j] += neg ? lg : ng;
            }
        }
    }

    // U-sums over c3 with q3 weights (C combo: c0C = 3-(j>>2), c3C = 3-(j&3))
    float UA0[2], UA1[2], UC2[2], UC3[2];
#pragma unroll
    for (int s = 0; s < 2; ++s) {
        UA0[s] = lpA[s][0]*q3v0[s] + lpA[s][1]*q3v1[s] + lpA[s][2]*q3v2[s] + lpA[s][3]*q3v3[s];
        UA1[s] = lpA[s][4]*q3v0[s] + lpA[s][5]*q3v1[s] + lpA[s][6]*q3v2[s] + lpA[s][7]*q3v3[s];
        UC3[s] = lpC[s][0]*q3v3[s] + lpC[s][1]*q3v2[s] + lpC[s][2]*q3v1[s] + lpC[s][3]*q3v0[s];
        UC2[s] = lpC[s][4]*q3v3[s] + lpC[s][5]*q3v2[s] + lpC[s][6]*q3v1[s] + lpC[s][7]*q3v0[s];
    }

    // ======== round 0 (groups = c0, in-lane) ========
    float JA[2], JC[2], Pin[2][4], Qin[2][4];
#pragma unroll
    for (int s = 0; s < 2; ++s) {
        float preQ  = q1A[s] * q2A[s];
        float preQC = q1C[s] * q2C[s];
        float VA0 = UA0[s] * preQ,  VA1 = UA1[s] * preQ;    // -> ex cols 0,1
        float VC2 = UC2[s] * preQC, VC3 = UC3[s] * preQC;   // -> ex cols 2,3
        bool bb = (u & 1);
        float S01 = (bb ? VA1 : VA0) + SWZX(bb ? VA0 : VA1, 1);
        float S23 = (bb ? VC3 : VC2) + SWZX(bb ? VC2 : VC3, 1);
        S01 += SWZX(S01, 2); S01 += SWZX(S01, 4); S01 += SWZX(S01, 8);
        S23 += SWZX(S23, 2); S23 += SWZX(S23, 4); S23 += SWZX(S23, 8);
        float exD = (col & 2) ? S23 : S01;
        float bl = fmaf(alm1, slqD[s], alpha * exD);
        slqD[s] = (row == 0) ? bl : slqD[s];
        float qD = softmax_all(slqD[s]);
        float q0v0 = swz<0, 0, 0x10>(qD);
        float q0v1 = swz<0, 1, 0x10>(qD);
        float q0v2 = swz<0, 2, 0x10>(qD);
        float q0v3 = swz<0, 3, 0x10>(qD);
        JA[s] = q0v0*UA0[s] + q0v1*UA1[s];        // reusable rounds 1-2
        JC[s] = q0v3*UC3[s] + q0v2*UC2[s];
        Pin[s][0] = lpA[s][0]*q0v0 + lpA[s][4]*q0v1;   // round-3 A-side per c3
        Pin[s][1] = lpA[s][1]*q0v0 + lpA[s][5]*q0v1;
        Pin[s][2] = lpA[s][2]*q0v0 + lpA[s][6]*q0v1;
        Pin[s][3] = lpA[s][3]*q0v0 + lpA[s][7]*q0v1;
        Qin[s][0] = lpC[s][3]*q0v3 + lpC[s][7]*q0v2;   // C-side: c3C=c -> j&3=3-c
        Qin[s][1] = lpC[s][2]*q0v3 + lpC[s][6]*q0v2;
        Qin[s][2] = lpC[s][1]*q0v3 + lpC[s][5]*q0v2;
        Qin[s][3] = lpC[s][0]*q0v3 + lpC[s][4]*q0v2;
    }

    // ======== round 1 (groups = c1 = bits 2-3) ========
#pragma unroll
    for (int s = 0; s < 2; ++s) {
        float SA = q2A[s] * JA[s], SC = q2C[s] * JC[s];
        SA += SWZX(SA, 1); SA += SWZX(SA, 2);       // sum over c2
        SC += SWZX(SC, 1); SC += SWZX(SC, 2);
        float T = SA + SWZX(SC, 12);                // C of group c1^3 -> c1
        float exD = bperm(aR1, T);                  // ex[col]
        float bl = fmaf(alm1, slqD[s], alpha * exD);
        slqD[s] = (row == 1) ? bl : slqD[s];
        float qD = softmax_all(slqD[s]);
        q1A[s] = bperm(aQ1A, qD); q1C[s] = bperm(aQ1C, qD);
    }

    // ======== round 2 (groups = c2 = bits 0-1) ========
#pragma unroll
    for (int s = 0; s < 2; ++s) {
        float SA = q1A[s] * JA[s], SC = q1C[s] * JC[s];
        SA += SWZX(SA, 4); SA += SWZX(SA, 8);       // sum over c1
        SC += SWZX(SC, 4); SC += SWZX(SC, 8);
        float exD = SA + SWZX(SC, 3);               // lands on own lane: c2 == col
        float bl = fmaf(alm1, slqD[s], alpha * exD);
        slqD[s] = (row == 2) ? bl : slqD[s];
        float qD = softmax_all(slqD[s]);
        q2A[s] = swz<0, 8, 0x13>(qD);
        q2C[s] = swz<3, 8, 0x13>(qD);
    }

    // ======== round 3 (groups = c3, in-lane) ========
#pragma unroll
    for (int s = 0; s < 2; ++s) {
        float WA = q1A[s] * q2A[s], WC = q1C[s] * q2C[s];
        float V0 = Pin[s][0]*WA + Qin[s][0]*WC;
        float V1 = Pin[s][1]*WA + Qin[s][1]*WC;
        float V2 = Pin[s][2]*WA + Qin[s][2]*WC;
        float V3 = Pin[s][3]*WA + Qin[s][3]*WC;
        bool bb = (u & 1);
        float S01 = (bb ? V1 : V0) + SWZX(bb ? V0 : V1, 1);
        float S23 = (bb ? V3 : V2) + SWZX(bb ? V2 : V3, 1);
        S01 += SWZX(S01, 2); S01 += SWZX(S01, 4); S01 += SWZX(S01, 8);
        S23 += SWZX(S23, 2); S23 += SWZX(S23, 4); S23 += SWZX(S23, 8);
        float exD = (col & 2) ? S23 : S01;
        float bl = fmaf(alm1, slqD[s], alpha * exD);
        slqD[s] = (row == 3) ? bl : slqD[s];
    }

    // ---- single final renorm (all rows), then coalesced stores ----
#pragma unroll
    for (int s = 0; s < 2; ++s) {
        float m1 = fmaxf(slqD[s], SWZX(slqD[s], 1));
        float m  = fmaxf(m1, SWZX(m1, 2));
        slqD[s] -= m;
        if (valid[s]) {
            out[(size_t)item[s] * 16 + u] = slqD[s] * LN2F;
        }
    }
}

extern "C" void kernel_launch(void* const* d_in, const int* in_sizes, int n_in,
                              void* d_out, int out_size, void* d_ws, size_t ws_size,
                              hipStream_t stream) {
    const float* log_qi = (const float*)d_in[0];
    const float* G      = (const float*)d_in[1];
    const float* rho    = (const float*)d_in[2];
    // d_in[3] = n_var — unused by the reference
    const float* alpha  = (const float*)d_in[4];
    float* out = (float*)d_out;

    const int N = in_sizes[2];                 // 32768 batch items
    const int blocks = (N + 31) / 32;          // 32 items per block (8 per wave)
    mfnet_layer_kernel<<<blocks, 256, 0, stream>>>(log_qi, G, rho, alpha, out, N);
}